// Round 1
// 337.777 us; speedup vs baseline: 1.0685x; 1.0685x over previous
//
#include <hip/hip_runtime.h>

// CoarseMatching dual-softmax on MI355X — round 3.
// N=2, L=S=4800, C=256. sim = f0.f1^T/(256*0.1); conf = softmax_l * softmax_s.
// GEMM: f16 hi/lo 2-term split -> K=512 f16 MFMA GEMM (was bf16 3-term K=768).
//   dot = a_hi.b_hi + a_lo.b_hi  (drops a_hi.b_lo ~2^-12 rel; conf err ~1e-8 abs)
// BK=64 per stage (2 k-substeps of 32), 32KB LDS, XOR 16B-slot swizzle.
// Fused epilogue: e = exp(sim*alpha), write e, atomic row/col sums.
// conf pass: conf = e^2 * (1/rs) * (1/cs) in place; finalize gated by rowmax.

#define Ncst 2
#define Lc 4800
#define Sc 4800
#define Cc 256
#define K2 512          // 2*C expanded K (f16 hi|lo for A, hi|hi for B)
#define LP 4864         // 4800 padded to 38*128
#define THRC 0.2f

typedef float f32x4 __attribute__((ext_vector_type(4)));
typedef _Float16 f16x8 __attribute__((ext_vector_type(8)));

#define AS1(p) ((__attribute__((address_space(1))) void*)(p))
#define AS3(p) ((__attribute__((address_space(3))) void*)(p))

// ---------------- init: zero the atomic sum accumulators ---------------------
__global__ __launch_bounds__(256) void init_kernel(float* __restrict__ rs, float* __restrict__ cs)
{
    int i = blockIdx.x * 256 + threadIdx.x;
    if (i < Ncst * Lc) { rs[i] = 0.f; cs[i] = 0.f; }
}

// ---------------- conversion: A2 [N][LP][512], B2 [N][LP][512] f16 -----------
// A2 segments: [a_hi | a_lo]; B2: [b_hi | b_hi]
// => dot over 512 = hi.hi + lo.hi.  Vectorized: 8 k per thread.
__global__ __launch_bounds__(256) void convert_kernel(
    const float* __restrict__ f0, const float* __restrict__ f1,
    unsigned short* __restrict__ A2, unsigned short* __restrict__ B2)
{
    int idx = blockIdx.x * 256 + threadIdx.x;      // over N*LP*(C/8)
    if (idx >= Ncst * LP * (Cc / 8)) return;
    int k8  = idx & (Cc / 8 - 1);                  // 0..31
    int row = (idx >> 5) % LP;
    int n   = idx / (LP * (Cc / 8));
    size_t base = ((size_t)n * LP + row) * K2 + k8 * 8;

    float av[8], bv[8];
    if (row < Lc) {
        const float4* pa = (const float4*)(f0 + ((size_t)n * Lc + row) * Cc + k8 * 8);
        float4 a0 = pa[0], a1 = pa[1];
        av[0]=a0.x; av[1]=a0.y; av[2]=a0.z; av[3]=a0.w;
        av[4]=a1.x; av[5]=a1.y; av[6]=a1.z; av[7]=a1.w;
        const float4* pb = (const float4*)(f1 + ((size_t)n * Sc + row) * Cc + k8 * 8);
        float4 b0 = pb[0], b1 = pb[1];
        bv[0]=b0.x; bv[1]=b0.y; bv[2]=b0.z; bv[3]=b0.w;
        bv[4]=b1.x; bv[5]=b1.y; bv[6]=b1.z; bv[7]=b1.w;
    } else {
        for (int i = 0; i < 8; ++i) { av[i] = 0.f; bv[i] = 0.f; }
    }

    _Float16 ahi[8], alo[8], bhi[8];
#pragma unroll
    for (int i = 0; i < 8; ++i) {
        _Float16 h = (_Float16)av[i];
        ahi[i] = h;
        alo[i] = (_Float16)(av[i] - (float)h);
        bhi[i] = (_Float16)bv[i];
    }
    *(uint4*)&A2[base]       = *(uint4*)ahi;
    *(uint4*)&A2[base + 256] = *(uint4*)alo;
    *(uint4*)&B2[base]       = *(uint4*)bhi;
    *(uint4*)&B2[base + 256] = *(uint4*)bhi;
}

// ---------------- GEMM + fused exp + row/col sum accumulation ----------------
// 128x128 tile, 4 waves (2x2), each wave 64x64 via 4x4 grid of 16x16x32 MFMAs,
// BK=64 per stage (2 k-substeps). LDS: 16B-slot XOR swizzle over 8 q-slots:
// slot(row,q) = row*8 + (q ^ (row&7)) -> fragment ds_read_b128 is 2 lanes/bank.
__global__ __launch_bounds__(256) void gemm_kernel(
    const unsigned short* __restrict__ A2, const unsigned short* __restrict__ B2,
    float* __restrict__ eout, float* __restrict__ rs, float* __restrict__ cs)
{
    __shared__ unsigned short lA[128 * 64];   // 16 KB: 1024 slots of 8 elems
    __shared__ unsigned short lB[128 * 64];

    // bijective XCD-aware swizzle: grid = 38*38*2 = 2888 = 8*361
    int flat = blockIdx.x + 38 * blockIdx.y + 1444 * blockIdx.z;
    int m    = (flat & 7) * 361 + (flat >> 3);
    const int tn = m % 38;
    const int tm = (m / 38) % 38;
    const int n  = m / 1444;

    const int tid  = threadIdx.x;
    const int wave = tid >> 6;
    const int lane = tid & 63;
    const int wm   = wave >> 1;     // 0..1
    const int wn   = wave & 1;      // 0..1
    const int ml   = lane & 15;
    const int kq   = lane >> 4;     // 0..3

    const unsigned short* Ab = A2 + ((size_t)n * LP + (size_t)tm * 128) * K2;
    const unsigned short* Bb = B2 + ((size_t)n * LP + (size_t)tn * 128) * K2;

    f32x4 acc[4][4] = {};

    for (int k0 = 0; k0 < K2; k0 += 64) {
        __syncthreads();
        // stage 16KB per matrix: 1024 slots of 16B; slot s <- (row=s>>3, q=(s&7)^(row&7))
#pragma unroll
        for (int cc = 0; cc < 4; ++cc) {
            int slot = (wave * 4 + cc) * 64 + lane;  // 0..1023, dest = base + lane*16
            int row  = slot >> 3;
            int q    = (slot & 7) ^ (row & 7);
            const unsigned short* ga = Ab + (size_t)row * K2 + (k0 + q * 8);
            const unsigned short* gb = Bb + (size_t)row * K2 + (k0 + q * 8);
            __builtin_amdgcn_global_load_lds(AS1(ga), AS3(lA + (size_t)slot * 8), 16, 0, 0);
            __builtin_amdgcn_global_load_lds(AS1(gb), AS3(lB + (size_t)slot * 8), 16, 0, 0);
        }
        __syncthreads();

#pragma unroll
        for (int s = 0; s < 2; ++s) {
            f16x8 af[4], bfr[4];
#pragma unroll
            for (int i = 0; i < 4; ++i) {
                int arow = wm * 64 + i * 16 + ml;
                int aq   = (s * 4 + kq) ^ (arow & 7);
                af[i] = *(const f16x8*)&lA[((size_t)arow * 8 + aq) * 8];
                int brow = wn * 64 + i * 16 + ml;
                int bq   = (s * 4 + kq) ^ (brow & 7);
                bfr[i] = *(const f16x8*)&lB[((size_t)brow * 8 + bq) * 8];
            }
#pragma unroll
            for (int i = 0; i < 4; ++i)
#pragma unroll
                for (int j = 0; j < 4; ++j)
                    acc[i][j] = __builtin_amdgcn_mfma_f32_16x16x32_f16(af[i], bfr[j], acc[i][j], 0, 0, 0);
        }
    }

    // ---- epilogue: e = exp(alpha*sim); store; accumulate row/col sums ----
    // D[row][col]: col = lane&15, row = (lane>>4)*4 + r
    const float alpha = 5.0f / 128.0f;          // 1/(256*0.1), exact in fp32
#pragma unroll
    for (int i = 0; i < 4; ++i) {
#pragma unroll
        for (int r = 0; r < 4; ++r) {
            int gl = tm * 128 + wm * 64 + i * 16 + kq * 4 + r;
            bool rok = gl < Lc;
#pragma unroll
            for (int j = 0; j < 4; ++j) {
                int gs = tn * 128 + wn * 64 + j * 16 + ml;
                bool ok = rok && (gs < Sc);
                float ev = ok ? __expf(acc[i][j][r] * alpha) : 0.f;
                acc[i][j][r] = ev;
                if (ok) eout[((size_t)n * Lc + gl) * Sc + gs] = ev;
            }
        }
    }
    // row sums: reduce over j and over ml lanes (xor 1,2,4,8 stays in quarter)
#pragma unroll
    for (int i = 0; i < 4; ++i) {
#pragma unroll
        for (int r = 0; r < 4; ++r) {
            float rp = acc[i][0][r] + acc[i][1][r] + acc[i][2][r] + acc[i][3][r];
            rp += __shfl_xor(rp, 1);
            rp += __shfl_xor(rp, 2);
            rp += __shfl_xor(rp, 4);
            rp += __shfl_xor(rp, 8);
            int gl = tm * 128 + wm * 64 + i * 16 + kq * 4 + r;
            if (ml == 0 && gl < Lc) atomicAdd(&rs[(size_t)n * Lc + gl], rp);
        }
    }
    // col sums: reduce over i,r and over kq (xor 16, 32)
#pragma unroll
    for (int j = 0; j < 4; ++j) {
        float cp = 0.f;
#pragma unroll
        for (int i = 0; i < 4; ++i)
#pragma unroll
            for (int r = 0; r < 4; ++r) cp += acc[i][j][r];
        cp += __shfl_xor(cp, 16);
        cp += __shfl_xor(cp, 32);
        int gs = tn * 128 + wn * 64 + j * 16 + ml;
        if (kq == 0 && gs < Sc) atomicAdd(&cs[(size_t)n * Sc + gs], cp);
    }
}

// ---------------- reciprocal of sums ----------------------------------------
__global__ __launch_bounds__(256) void inv_kernel(
    const float* __restrict__ rs, const float* __restrict__ cs,
    float* __restrict__ rsinv, float* __restrict__ csinv)
{
    int i = blockIdx.x * 256 + threadIdx.x;
    if (i < Ncst * Lc) { rsinv[i] = 1.0f / rs[i]; csinv[i] = 1.0f / cs[i]; }
}

// ---------------- conf: in-place e -> conf = e^2*rsinv*csinv; row conf max ---
__global__ __launch_bounds__(256) void conf_kernel(
    float* __restrict__ confio,
    const float* __restrict__ rsinv, const float* __restrict__ csinv,
    float* __restrict__ rcm)
{
    __shared__ float sw[4];
    int b = blockIdx.x;                          // n*Lc + l
    int n = b / Lc;
    f32x4* row = (f32x4*)(confio + (size_t)b * Sc);
    const f32x4* civ = (const f32x4*)(csinv + (size_t)n * Sc);
    int tid = threadIdx.x;
    float riv = rsinv[b];
    float lmax = 0.f;
    for (int v = tid; v < Sc / 4; v += 256) {
        f32x4 e4 = row[v];
        f32x4 c4 = civ[v];
        f32x4 o  = e4 * e4 * riv * c4;
        row[v] = o;
        lmax = fmaxf(lmax, fmaxf(fmaxf(o.x, o.y), fmaxf(o.z, o.w)));
    }
#pragma unroll
    for (int off = 1; off < 64; off <<= 1) lmax = fmaxf(lmax, __shfl_xor(lmax, off));
    if ((tid & 63) == 0) sw[tid >> 6] = lmax;
    __syncthreads();
    if (tid == 0) rcm[b] = fmaxf(fmaxf(sw[0], sw[1]), fmaxf(sw[2], sw[3]));
}

// ---------------- finalize: threshold + border + mutual-NN -------------------
// Gated by rowmax_conf > THR (any mask-true entry must equal rowmax > THR).
__global__ __launch_bounds__(256) void finalize_kernel(
    const float* __restrict__ conf, const float* __restrict__ rcm,
    const int* __restrict__ h0p, const int* __restrict__ w0p,
    const int* __restrict__ h1p, const int* __restrict__ w1p,
    float* __restrict__ out_match, float* __restrict__ out_j, float* __restrict__ out_mconf)
{
    int i = blockIdx.x * 256 + threadIdx.x;      // n*Lc + l
    if (i >= Ncst * Lc) return;
    int n = i / Lc, l = i % Lc;
    float mm = rcm[i];
    float fm = 0.f, fj = 0.f, fc = 0.f;
    if (mm > THRC) {
        int w0 = *w0p, w1 = *w1p;
        if ((l / w0) >= 2 && (l % w0) >= 2) {
            const float* rowp = conf + ((size_t)n * Lc + l) * Sc;
            for (int s = 0; s < Sc; ++s) {
                float c = rowp[s];
                if (c == mm && (s / w1) >= 2 && (s % w1) >= 2) {
                    bool ismax = true;
                    const float* colp = conf + (size_t)n * Lc * Sc + s;
                    for (int lp = 0; lp < Lc; ++lp) {
                        if (colp[(size_t)lp * Sc] > c) { ismax = false; break; }
                    }
                    if (ismax) { fm = 1.f; fj = (float)s; fc = c; break; }
                }
            }
        }
    }
    out_match[i] = fm; out_j[i] = fj; out_mconf[i] = fc;
}

extern "C" void kernel_launch(void* const* d_in, const int* in_sizes, int n_in,
                              void* d_out, int out_size, void* d_ws, size_t ws_size,
                              hipStream_t stream) {
    const float* f0 = (const float*)d_in[0];
    const float* f1 = (const float*)d_in[1];
    const int* h0p = (const int*)d_in[2];
    const int* w0p = (const int*)d_in[3];
    const int* h1p = (const int*)d_in[4];
    const int* w1p = (const int*)d_in[5];

    // workspace layout (bytes); total ~20.1 MB
    char* ws = (char*)d_ws;
    unsigned short* A2 = (unsigned short*)ws;                  // 9,961,472 B
    unsigned short* B2 = (unsigned short*)(ws + 9961472);      // 9,961,472 B
    float* rs    = (float*)(ws + 19922944);                    // 38,400 B each
    float* cs    = (float*)(ws + 19961344);
    float* rsinv = (float*)(ws + 19999744);
    float* csinv = (float*)(ws + 20038144);
    float* rcm   = (float*)(ws + 20076544);

    float* conf      = (float*)d_out;                          // [N][L][S]: e then conf
    float* out_match = conf + (size_t)Ncst * Lc * Sc;
    float* out_j     = out_match + Ncst * Lc;
    float* out_mconf = out_j + Ncst * Lc;

    init_kernel<<<(Ncst * Lc + 255) / 256, 256, 0, stream>>>(rs, cs);

    convert_kernel<<<(Ncst * LP * (Cc / 8) + 255) / 256, 256, 0, stream>>>(f0, f1, A2, B2);

    dim3 gg(LP / 128, LP / 128, Ncst);   // 38 x 38 x 2
    gemm_kernel<<<gg, 256, 0, stream>>>(A2, B2, conf, rs, cs);

    inv_kernel<<<(Ncst * Lc + 255) / 256, 256, 0, stream>>>(rs, cs, rsinv, csinv);

    conf_kernel<<<Ncst * Lc, 256, 0, stream>>>(conf, rsinv, csinv, rcm);

    finalize_kernel<<<(Ncst * Lc + 255) / 256, 256, 0, stream>>>(
        conf, rcm, h0p, w0p, h1p, w1p, out_match, out_j, out_mconf);
}